// Round 1
// baseline (5223.063 us; speedup 1.0000x reference)
//
#include <hip/hip_runtime.h>
#include <math.h>

// ---------------- problem constants ----------------
#define NN      1000      // nodes
#define TLEN    4000
#define BB      16        // batch
#define SS      12        // input window
#define HH      12        // horizon
#define HID     64
#define INF     65        // 1 + HID
#define C1N     8
#define C2N     16
#define KW      10
#define L1LEN   3991      // conv1 out
#define L2LEN   3982      // conv2 out
#define DD      128
#define HE      128

// padded GEMM dims
#define MP      1024      // padded rows (i)
#define KP      1024      // padded K (j)
#define CP      1088      // padded cols (b*65+f), 17*64
#define CF      1040      // valid cols = 16*65

// ---------------- stage 1: fused conv1+conv2+pool ----------------
#define TT 512
__global__ __launch_bounds__(256) void s1_conv(const float* __restrict__ ein,
        const float* __restrict__ w1, const float* __restrict__ b1c,
        const float* __restrict__ w2, const float* __restrict__ b2c,
        float* __restrict__ f_raw) {
    __shared__ float xb[TLEN];
    __shared__ float c1t[C1N][TT + KW];        // 8 x 522
    __shared__ float w1s[C1N * KW];
    __shared__ float w2s[C2N * C1N * KW];
    __shared__ float b1s[C1N], b2s[C2N];
    __shared__ float red[256];
    int n = blockIdx.x, t = threadIdx.x;
    for (int i = t; i < TLEN; i += 256) xb[i] = ein[n * TLEN + i];
    for (int i = t; i < C1N * KW; i += 256) w1s[i] = w1[i];
    for (int i = t; i < C2N * C1N * KW; i += 256) w2s[i] = w2[i];
    if (t < C1N) b1s[t] = b1c[t];
    if (t < C2N) b2s[t] = b2c[t];
    float pool[C2N];
#pragma unroll
    for (int c = 0; c < C2N; c++) pool[c] = 0.f;
    __syncthreads();

    for (int t0 = 0; t0 < L2LEN; t0 += TT) {
        int c1len = min(TT + KW - 1, L1LEN - t0);   // conv1 entries needed this tile
        // conv1 into LDS
        for (int c = 0; c < C1N; c++) {
            for (int p = t; p < c1len; p += 256) {
                float acc = b1s[c];
#pragma unroll
                for (int k = 0; k < KW; k++) acc += xb[t0 + p + k] * w1s[c * KW + k];
                c1t[c][p] = fmaxf(acc, 0.f);
            }
        }
        __syncthreads();
        // conv2 + pooled accumulate; each thread 2 positions
        int q0 = t0 + t, q1 = t0 + t + 256;
        bool v0 = (q0 < L2LEN), v1 = (q1 < L2LEN) && (t + 256 < TT);
        if (v0 || v1) {
            float a0[C2N], a1[C2N];
#pragma unroll
            for (int c = 0; c < C2N; c++) { a0[c] = b2s[c]; a1[c] = b2s[c]; }
            int l0 = t, l1 = t + 256;
            for (int c1 = 0; c1 < C1N; c1++) {
#pragma unroll
                for (int k = 0; k < KW; k++) {
                    float x0 = v0 ? c1t[c1][l0 + k] : 0.f;
                    float x1 = v1 ? c1t[c1][l1 + k] : 0.f;
#pragma unroll
                    for (int c2 = 0; c2 < C2N; c2++) {
                        float w = w2s[c2 * (C1N * KW) + c1 * KW + k];
                        a0[c2] += x0 * w;
                        a1[c2] += x1 * w;
                    }
                }
            }
#pragma unroll
            for (int c2 = 0; c2 < C2N; c2++) {
                if (v0) pool[c2] += fmaxf(a0[c2], 0.f);
                if (v1) pool[c2] += fmaxf(a1[c2], 0.f);
            }
        }
        __syncthreads();
    }
    // reduce pool over 256 threads
    for (int c2 = 0; c2 < C2N; c2++) {
        red[t] = pool[c2];
        __syncthreads();
        for (int s = 128; s > 0; s >>= 1) {
            if (t < s) red[t] += red[t + s];
            __syncthreads();
        }
        if (t == 0) f_raw[n * C2N + c2] = red[0] / 3982.0f;
        __syncthreads();
    }
}

// ---------------- stage 1b: fc + relu ----------------
__global__ __launch_bounds__(128) void fc_relu(const float* __restrict__ f_raw,
        const float* __restrict__ fcw, const float* __restrict__ fcb,
        float* __restrict__ f) {
    __shared__ float fr[C2N];
    int n = blockIdx.x, t = threadIdx.x;
    if (t < C2N) fr[t] = f_raw[n * C2N + t];
    __syncthreads();
    float acc = fcb[t];
#pragma unroll
    for (int c = 0; c < C2N; c++) acc += fr[c] * fcw[c * DD + t];
    f[n * DD + t] = fmaxf(acc, 0.f);
}

// ---------------- stage 1c: fa = f@Wa, fb = f@Wb ----------------
__global__ __launch_bounds__(128) void fafb_k(const float* __restrict__ f,
        const float* __restrict__ Wa, const float* __restrict__ Wb,
        float* __restrict__ fa, float* __restrict__ fb) {
    __shared__ float fr[DD];
    int n = blockIdx.x, t = threadIdx.x;
    fr[t] = f[n * DD + t];
    __syncthreads();
    float a = 0.f, b = 0.f;
    for (int k = 0; k < DD; k++) {
        float fv = fr[k];
        a += fv * Wa[k * HE + t];
        b += fv * Wb[k * HE + t];
    }
    fa[n * HE + t] = a;
    fb[n * HE + t] = b;
}

// ---------------- stage 2: edge MLP + gumbel hard mask ----------------
__global__ __launch_bounds__(256) void edge_mask(const float* __restrict__ fa,
        const float* __restrict__ fb, const float* __restrict__ b1,
        const float* __restrict__ W2, const float* __restrict__ b2,
        const float* __restrict__ u_noise, float* __restrict__ mask) {
    __shared__ float sfa[16][129], sfb[16][129];
    __shared__ float w20[HE], w21[HE], b1s[HE];
    __shared__ float b2s[2];
    int t = threadIdx.x;
    int i0 = blockIdx.x * 16, j0 = blockIdx.y * 16;
    for (int idx = t; idx < 16 * HE; idx += 256) {
        int r = idx >> 7, c = idx & 127;
        sfa[r][c] = (i0 + r < NN) ? fa[(i0 + r) * HE + c] : 0.f;
        sfb[r][c] = (j0 + r < NN) ? fb[(j0 + r) * HE + c] : 0.f;
    }
    if (t < HE) { w20[t] = W2[t * 2]; w21[t] = W2[t * 2 + 1]; b1s[t] = b1[t]; }
    if (t < 2) b2s[t] = b2[t];
    __syncthreads();
    int ti = t >> 4, tj = t & 15;
    int i = i0 + ti, j = j0 + tj;
    if (i >= NN || j >= NN) return;
    double l0 = 0.0, l1 = 0.0;
    for (int dd = 0; dd < HE; dd++) {
        float hv = fmaxf(sfa[ti][dd] + sfb[tj][dd] + b1s[dd], 0.f);
        l0 += (double)hv * (double)w20[dd];
        l1 += (double)hv * (double)w21[dd];
    }
    long e = (long)i * NN + j;
    double u0 = (double)u_noise[2 * e], u1 = (double)u_noise[2 * e + 1];
    double g0 = -log(-log(u0 + 1e-10) + 1e-10);
    double g1 = -log(-log(u1 + 1e-10) + 1e-10);
    double s0 = l0 + (double)b2s[0] + g0;
    double s1 = l1 + (double)b2s[1] + g1;
    float mv = (i == j) ? 0.f : ((s0 >= s1) ? 1.f : 0.f);
    mask[e] = mv;
}

// ---------------- row degree ----------------
__global__ __launch_bounds__(256) void row_deg(const float* __restrict__ mask,
        float* __restrict__ deg) {
    __shared__ float red[256];
    int i = blockIdx.x, t = threadIdx.x;
    float s = 0.f;
    for (int j = t; j < NN; j += 256) s += mask[i * NN + j];
    red[t] = s;
    __syncthreads();
    for (int w = 128; w > 0; w >>= 1) {
        if (t < w) red[t] += red[t + w];
        __syncthreads();
    }
    if (t == 0) deg[i] = red[0];
}

// ---------------- A = mask / (deg + 1e-6), zero-padded to 1024x1024 ----------------
__global__ __launch_bounds__(256) void make_A(const float* __restrict__ mask,
        const float* __restrict__ deg, float* __restrict__ A) {
    int idx = blockIdx.x * 256 + threadIdx.x;   // over 1024*1024
    int i = idx >> 10, j = idx & 1023;
    float v = 0.f;
    if (i < NN && j < NN) v = mask[i * NN + j] / (deg[i] + 1e-6f);
    A[idx] = v;
}

// ---------------- init zeros (h, ubuf, yprev region + cat2 buffer) ----------------
__global__ void init_zero(float* __restrict__ a, int na, float* __restrict__ b, int nb) {
    int stride = gridDim.x * blockDim.x;
    for (int i = blockIdx.x * blockDim.x + threadIdx.x; i < na; i += stride) a[i] = 0.f;
    for (int i = blockIdx.x * blockDim.x + threadIdx.x; i < nb; i += stride) b[i] = 0.f;
}

// ---------------- build cat = [x, h] in [j][b*65+f] layout, padded ----------------
__global__ __launch_bounds__(256) void build_cat(float* __restrict__ cat,
        const float* __restrict__ h, const float* __restrict__ inputs,
        const float* __restrict__ yprev, int dec_mode, int s) {
    int j = blockIdx.x, t = threadIdx.x;  // grid 1024
    for (int c = t; c < CP; c += 256) {
        float v = 0.f;
        if (j < NN && c < CF) {
            int b = c / INF, f = c - b * INF;
            if (f == 0)
                v = dec_mode ? yprev[b * NN + j] : inputs[(b * SS + s) * NN + j];
            else
                v = h[(b * NN + j) * HID + (f - 1)];
        }
        cat[j * CP + c] = v;
    }
}

// ---------------- fp32 tiled GEMM: C[MPxCP] = A[MPxKP] @ B[KPxCP] ----------------
#define GBM 64
#define GBN 64
#define GBK 16
__global__ __launch_bounds__(256) void gemm_f32(const float* __restrict__ A,
        const float* __restrict__ B, float* __restrict__ C) {
    __shared__ float As[GBK][GBM + 4];
    __shared__ float Bs[GBK][GBN + 4];
    int t = threadIdx.x;
    int tx = t & 15, ty = t >> 4;
    int bm = blockIdx.x * GBM, bn = blockIdx.y * GBN;
    float acc[4][4];
#pragma unroll
    for (int i = 0; i < 4; i++)
#pragma unroll
        for (int j = 0; j < 4; j++) acc[i][j] = 0.f;

    for (int k0 = 0; k0 < KP; k0 += GBK) {
#pragma unroll
        for (int l = 0; l < 4; l++) {
            int idx = t + l * 256;
            int m = idx >> 4, kk = idx & 15;
            As[kk][m] = A[(bm + m) * KP + k0 + kk];
        }
#pragma unroll
        for (int l = 0; l < 4; l++) {
            int idx = t + l * 256;
            int kk = idx >> 6, nn2 = idx & 63;
            Bs[kk][nn2] = B[(k0 + kk) * CP + bn + nn2];
        }
        __syncthreads();
#pragma unroll
        for (int kk = 0; kk < GBK; kk++) {
            float4 av = *(const float4*)&As[kk][ty * 4];
            float4 bv = *(const float4*)&Bs[kk][tx * 4];
            float a[4] = {av.x, av.y, av.z, av.w};
            float b[4] = {bv.x, bv.y, bv.z, bv.w};
#pragma unroll
            for (int i = 0; i < 4; i++)
#pragma unroll
                for (int j = 0; j < 4; j++) acc[i][j] += a[i] * b[j];
        }
        __syncthreads();
    }
#pragma unroll
    for (int i = 0; i < 4; i++)
#pragma unroll
        for (int j = 0; j < 4; j++)
            C[(bm + ty * 4 + i) * CP + bn + tx * 4 + j] = acc[i][j];
}

// ---------------- GRU gate r,u: ru = sigmoid(cat@W0 + agg@W1 + b); cat2 = [x, r*h] ----------------
__global__ __launch_bounds__(256) void gru_ru(const float* __restrict__ cat,
        const float* __restrict__ agg, const float* __restrict__ W0,
        const float* __restrict__ W1, const float* __restrict__ bru,
        const float* __restrict__ h, float* __restrict__ cat2,
        float* __restrict__ ubuf) {
    __shared__ float rc[8][INF + 1], ra[8][INF + 1];
    __shared__ float brs[2 * HID];
    int t = threadIdx.x;
    int row0 = blockIdx.x * 8;
    if (t < 2 * HID) brs[t] = bru[t];
    for (int i = t; i < 8 * INF; i += 256) {
        int rl = i / INF, f = i - rl * INF;
        int row = row0 + rl;
        int b = row / NN, ii = row - b * NN;
        rc[rl][f] = cat[ii * CP + b * INF + f];
        ra[rl][f] = agg[ii * CP + b * INF + f];
    }
    __syncthreads();
    int d = t & 127, half = t >> 7;   // two halves of the block each own 4 rows
    float acc0 = brs[d], acc1 = acc0, acc2 = acc0, acc3 = acc0;
    for (int f = 0; f < INF; f++) {
        float w0 = W0[f * (2 * HID) + d];
        float w1 = W1[f * (2 * HID) + d];
        acc0 += rc[half][f] * w0 + ra[half][f] * w1;
        acc1 += rc[half + 2][f] * w0 + ra[half + 2][f] * w1;
        acc2 += rc[half + 4][f] * w0 + ra[half + 4][f] * w1;
        acc3 += rc[half + 6][f] * w0 + ra[half + 6][f] * w1;
    }
    float accs[4] = {acc0, acc1, acc2, acc3};
#pragma unroll
    for (int p = 0; p < 4; p++) {
        int rl = half + 2 * p;
        int row = row0 + rl;
        int b = row / NN, ii = row - b * NN;
        float v = 1.f / (1.f + expf(-accs[p]));
        if (d < HID) {
            cat2[ii * CP + b * INF + 1 + d] = v * h[row * HID + d];
        } else {
            ubuf[row * HID + (d - HID)] = v;
        }
        if (d == 127) cat2[ii * CP + b * INF] = rc[rl][0];   // x passthrough
    }
}

// ---------------- GRU candidate + state update (+ optional projection) ----------------
__global__ __launch_bounds__(256) void gru_c(const float* __restrict__ cat2,
        const float* __restrict__ agg2, const float* __restrict__ Wc0,
        const float* __restrict__ Wc1, const float* __restrict__ bc,
        const float* __restrict__ ubuf, float* __restrict__ h,
        const float* __restrict__ proj_w, const float* __restrict__ proj_b,
        int do_proj, int hstep, float* __restrict__ outp, float* __restrict__ yprev) {
    __shared__ float W0s[INF * HID], W1s[INF * HID];
    __shared__ float rc[8][INF + 1], ra[8][INF + 1];
    __shared__ float bcs[HID];
    int t = threadIdx.x;
    int row0 = blockIdx.x * 8;
    for (int i = t; i < INF * HID; i += 256) { W0s[i] = Wc0[i]; W1s[i] = Wc1[i]; }
    if (t < HID) bcs[t] = bc[t];
    for (int i = t; i < 8 * INF; i += 256) {
        int rl = i / INF, f = i - rl * INF;
        int row = row0 + rl;
        int b = row / NN, ii = row - b * NN;
        rc[rl][f] = cat2[ii * CP + b * INF + f];
        ra[rl][f] = agg2[ii * CP + b * INF + f];
    }
    __syncthreads();
    int d = t & 63, wv = t >> 6;        // one wave per row, two rows per wave
    float acc0 = bcs[d], acc1 = bcs[d];
    for (int f = 0; f < INF; f++) {
        float w0 = W0s[f * HID + d];
        float w1 = W1s[f * HID + d];
        acc0 += rc[wv][f] * w0 + ra[wv][f] * w1;
        acc1 += rc[wv + 4][f] * w0 + ra[wv + 4][f] * w1;
    }
    float accs[2] = {acc0, acc1};
#pragma unroll
    for (int p = 0; p < 2; p++) {
        int rl = wv + 4 * p;
        int row = row0 + rl;
        float c = tanhf(accs[p]);
        float u = ubuf[row * HID + d];
        float hold = h[row * HID + d];
        float hn = u * hold + (1.f - u) * c;
        h[row * HID + d] = hn;
        if (do_proj) {
            float part = hn * proj_w[d];
#pragma unroll
            for (int off = 32; off > 0; off >>= 1) part += __shfl_xor(part, off);
            if (d == 0) {
                int b = row / NN, ii = row - b * NN;
                float yo = part + proj_b[0];
                outp[(b * HH + hstep) * NN + ii] = yo;
                yprev[row] = yo;
            }
        }
    }
}

// ---------------- loss ----------------
__global__ __launch_bounds__(256) void loss1(const float* __restrict__ outs,
        const float* __restrict__ tgt, float* __restrict__ part) {
    __shared__ float red[256];
    int t = blockIdx.x * 256 + threadIdx.x;
    float s = 0.f;
    for (int i = t; i < BB * HH * NN; i += 256 * 256) {
        float dd = outs[i] - tgt[i];
        s += dd * dd;
    }
    red[threadIdx.x] = s;
    __syncthreads();
    for (int w = 128; w > 0; w >>= 1) {
        if (threadIdx.x < w) red[threadIdx.x] += red[threadIdx.x + w];
        __syncthreads();
    }
    if (threadIdx.x == 0) part[blockIdx.x] = red[0];
}

__global__ __launch_bounds__(256) void loss2(const float* __restrict__ part,
        float* __restrict__ loss) {
    __shared__ double red[256];
    int t = threadIdx.x;
    red[t] = (double)part[t];
    __syncthreads();
    for (int w = 128; w > 0; w >>= 1) {
        if (t < w) red[t] += red[t + w];
        __syncthreads();
    }
    if (t == 0) loss[0] = (float)(red[0] / (double)(BB * HH * NN));
}

// ---------------- host ----------------
extern "C" void kernel_launch(void* const* d_in, const int* in_sizes, int n_in,
                              void* d_out, int out_size, void* d_ws, size_t ws_size,
                              hipStream_t stream) {
    const float* inputs  = (const float*)d_in[0];
    const float* ein     = (const float*)d_in[1];
    const float* targets = (const float*)d_in[2];
    const float* u_noise = (const float*)d_in[3];
    const float* c1w = (const float*)d_in[4];
    const float* c1b = (const float*)d_in[5];
    const float* c2w = (const float*)d_in[6];
    const float* c2b = (const float*)d_in[7];
    const float* fcw = (const float*)d_in[8];
    const float* fcb = (const float*)d_in[9];
    const float* Wa  = (const float*)d_in[10];
    const float* Wb  = (const float*)d_in[11];
    const float* b1  = (const float*)d_in[12];
    const float* W2  = (const float*)d_in[13];
    const float* b2  = (const float*)d_in[14];
    const float* eWru0 = (const float*)d_in[15];
    const float* eWru1 = (const float*)d_in[16];
    const float* ebru  = (const float*)d_in[17];
    const float* eWc0  = (const float*)d_in[18];
    const float* eWc1  = (const float*)d_in[19];
    const float* ebc   = (const float*)d_in[20];
    const float* dWru0 = (const float*)d_in[21];
    const float* dWru1 = (const float*)d_in[22];
    const float* dbru  = (const float*)d_in[23];
    const float* dWc0  = (const float*)d_in[24];
    const float* dWc1  = (const float*)d_in[25];
    const float* dbc   = (const float*)d_in[26];
    const float* projw = (const float*)d_in[27];
    const float* projb = (const float*)d_in[28];

    float* out = (float*)d_out;
    float* mask    = out;                       // [1000,1000]
    float* outputs = out + NN * NN;             // [16,12,1000]
    float* loss    = out + NN * NN + BB * HH * NN;

    float* ws = (float*)d_ws;
    // workspace layout (floats)
    float* f_raw = ws;                          // 16,000
    float* fbuf  = ws + 16000;                  // 128,000
    float* fa    = ws + 144000;                 // 128,000
    float* fb    = ws + 272000;                 // 128,000
    float* deg   = ws + 400000;                 // 1,000
    float* lossp = ws + 401000;                 // 256
    float* A_p   = ws + 401256;                 // 1024*1024 = 1,048,576
    float* cat   = ws + 1449832;                // 1024*1088 = 1,114,112
    float* agg   = ws + 2563944;
    float* cat2  = ws + 3678056;
    float* agg2  = ws + 4792168;
    float* h     = ws + 5906280;                // 16000*64 = 1,024,000
    float* ubuf  = ws + 6930280;                // 1,024,000
    float* yprev = ws + 7954280;                // 16,000  (end: 7,970,280 floats = 31.9 MB)

    // init: h + ubuf + yprev contiguous zeros, plus cat2 (padding must be 0)
    init_zero<<<2048, 256, 0, stream>>>(cat2, MP * CP, h, 1024000 + 1024000 + 16000);

    // stage 1: graph features
    s1_conv<<<NN, 256, 0, stream>>>(ein, c1w, c1b, c2w, c2b, f_raw);
    fc_relu<<<NN, 128, 0, stream>>>(f_raw, fcw, fcb, fbuf);
    fafb_k<<<NN, 128, 0, stream>>>(fbuf, Wa, Wb, fa, fb);

    // stage 2: edges
    edge_mask<<<dim3(63, 63), 256, 0, stream>>>(fa, fb, b1, W2, b2, u_noise, mask);
    row_deg<<<NN, 256, 0, stream>>>(mask, deg);
    make_A<<<4096, 256, 0, stream>>>(mask, deg, A_p);

    // encoder
    for (int s = 0; s < SS; s++) {
        build_cat<<<MP, 256, 0, stream>>>(cat, h, inputs, yprev, 0, s);
        gemm_f32<<<dim3(MP / GBM, CP / GBN), 256, 0, stream>>>(A_p, cat, agg);
        gru_ru<<<2000, 256, 0, stream>>>(cat, agg, eWru0, eWru1, ebru, h, cat2, ubuf);
        gemm_f32<<<dim3(MP / GBM, CP / GBN), 256, 0, stream>>>(A_p, cat2, agg2);
        gru_c<<<2000, 256, 0, stream>>>(cat2, agg2, eWc0, eWc1, ebc, ubuf, h,
                                        projw, projb, 0, 0, outputs, yprev);
    }
    // decoder
    for (int k = 0; k < HH; k++) {
        build_cat<<<MP, 256, 0, stream>>>(cat, h, inputs, yprev, 1, 0);
        gemm_f32<<<dim3(MP / GBM, CP / GBN), 256, 0, stream>>>(A_p, cat, agg);
        gru_ru<<<2000, 256, 0, stream>>>(cat, agg, dWru0, dWru1, dbru, h, cat2, ubuf);
        gemm_f32<<<dim3(MP / GBM, CP / GBN), 256, 0, stream>>>(A_p, cat2, agg2);
        gru_c<<<2000, 256, 0, stream>>>(cat2, agg2, dWc0, dWc1, dbc, ubuf, h,
                                        projw, projb, 1, k, outputs, yprev);
    }

    // loss
    loss1<<<256, 256, 0, stream>>>(outputs, targets, lossp);
    loss2<<<1, 256, 0, stream>>>(lossp, loss);
}

// Round 2
// 1960.471 us; speedup vs baseline: 2.6642x; 2.6642x over previous
//
#include <hip/hip_runtime.h>
#include <math.h>

// ---------------- problem constants ----------------
#define NN      1000
#define TLEN    4000
#define BB      16
#define SS      12
#define HH      12
#define HID     64
#define C1N     8
#define C2N     16
#define KW      10
#define L1LEN   3991
#define L2LEN   3982
#define DD      128
#define HE      128

typedef __bf16 bf16x8 __attribute__((ext_vector_type(8)));
typedef float  f32x4  __attribute__((ext_vector_type(4)));
typedef __attribute__((address_space(3))) unsigned int       as3_u32;
typedef const __attribute__((address_space(1))) unsigned int as1_u32;

__device__ __forceinline__ void glds16(const void* g, void* l) {
    __builtin_amdgcn_global_load_lds((as1_u32*)g, (as3_u32*)l, 16, 0, 0);
}

__device__ __forceinline__ bf16x8 pack8(float4 a, float4 b) {
    bf16x8 r;
    r[0] = (__bf16)a.x; r[1] = (__bf16)a.y; r[2] = (__bf16)a.z; r[3] = (__bf16)a.w;
    r[4] = (__bf16)b.x; r[5] = (__bf16)b.y; r[6] = (__bf16)b.z; r[7] = (__bf16)b.w;
    return r;
}

// ---------------- stage 1: fused conv1+conv2+pool (bit-identical math to r1) --
#define TT 512
__global__ __launch_bounds__(256) void s1_conv(const float* __restrict__ ein,
        const float* __restrict__ w1, const float* __restrict__ b1c,
        const float* __restrict__ w2, const float* __restrict__ b2c,
        float* __restrict__ f_raw) {
    __shared__ float xb[TLEN];
    __shared__ float c1t[C1N][TT + KW];
    __shared__ float w1s[C1N * KW];
    __shared__ __align__(16) float w2s[C1N * KW * C2N];   // [c1][k][c2]
    __shared__ float b1s[C1N], b2s[C2N];
    __shared__ float red[256];
    int n = blockIdx.x, t = threadIdx.x;
    for (int i = t; i < TLEN; i += 256) xb[i] = ein[n * TLEN + i];
    for (int i = t; i < C1N * KW; i += 256) w1s[i] = w1[i];
    for (int i = t; i < C1N * KW * C2N; i += 256) {
        int c2 = i & 15, c1k = i >> 4;
        w2s[i] = w2[c2 * (C1N * KW) + c1k];
    }
    if (t < C1N) b1s[t] = b1c[t];
    if (t < C2N) b2s[t] = b2c[t];
    float pool[C2N];
#pragma unroll
    for (int c = 0; c < C2N; c++) pool[c] = 0.f;
    __syncthreads();

    for (int t0 = 0; t0 < L2LEN; t0 += TT) {
        int c1len = min(TT + KW - 1, L1LEN - t0);
        for (int c = 0; c < C1N; c++) {
            for (int p = t; p < c1len; p += 256) {
                float acc = b1s[c];
#pragma unroll
                for (int k = 0; k < KW; k++) acc += xb[t0 + p + k] * w1s[c * KW + k];
                c1t[c][p] = fmaxf(acc, 0.f);
            }
        }
        __syncthreads();
        int q0 = t0 + t, q1 = t0 + t + 256;
        bool v0 = (q0 < L2LEN), v1 = (q1 < L2LEN) && (t + 256 < TT);
        if (v0 || v1) {
            float a0[C2N], a1[C2N];
#pragma unroll
            for (int c = 0; c < C2N; c++) { a0[c] = b2s[c]; a1[c] = b2s[c]; }
            int l0 = t, l1 = t + 256;
            for (int c1 = 0; c1 < C1N; c1++) {
#pragma unroll
                for (int k = 0; k < KW; k++) {
                    float x0 = v0 ? c1t[c1][l0 + k] : 0.f;
                    float x1 = v1 ? c1t[c1][l1 + k] : 0.f;
                    const float4* wp = (const float4*)&w2s[(c1 * KW + k) * C2N];
                    float4 wa = wp[0], wb = wp[1], wc = wp[2], wd = wp[3];
                    a0[0] += x0 * wa.x; a1[0] += x1 * wa.x;
                    a0[1] += x0 * wa.y; a1[1] += x1 * wa.y;
                    a0[2] += x0 * wa.z; a1[2] += x1 * wa.z;
                    a0[3] += x0 * wa.w; a1[3] += x1 * wa.w;
                    a0[4] += x0 * wb.x; a1[4] += x1 * wb.x;
                    a0[5] += x0 * wb.y; a1[5] += x1 * wb.y;
                    a0[6] += x0 * wb.z; a1[6] += x1 * wb.z;
                    a0[7] += x0 * wb.w; a1[7] += x1 * wb.w;
                    a0[8] += x0 * wc.x; a1[8] += x1 * wc.x;
                    a0[9] += x0 * wc.y; a1[9] += x1 * wc.y;
                    a0[10] += x0 * wc.z; a1[10] += x1 * wc.z;
                    a0[11] += x0 * wc.w; a1[11] += x1 * wc.w;
                    a0[12] += x0 * wd.x; a1[12] += x1 * wd.x;
                    a0[13] += x0 * wd.y; a1[13] += x1 * wd.y;
                    a0[14] += x0 * wd.z; a1[14] += x1 * wd.z;
                    a0[15] += x0 * wd.w; a1[15] += x1 * wd.w;
                }
            }
#pragma unroll
            for (int c2 = 0; c2 < C2N; c2++) {
                if (v0) pool[c2] += fmaxf(a0[c2], 0.f);
                if (v1) pool[c2] += fmaxf(a1[c2], 0.f);
            }
        }
        __syncthreads();
    }
    for (int c2 = 0; c2 < C2N; c2++) {
        red[t] = pool[c2];
        __syncthreads();
        for (int s = 128; s > 0; s >>= 1) {
            if (t < s) red[t] += red[t + s];
            __syncthreads();
        }
        if (t == 0) f_raw[n * C2N + c2] = red[0] / 3982.0f;
        __syncthreads();
    }
}

// ---------------- stage 1b/1c (unchanged) ----------------
__global__ __launch_bounds__(128) void fc_relu(const float* __restrict__ f_raw,
        const float* __restrict__ fcw, const float* __restrict__ fcb,
        float* __restrict__ f) {
    __shared__ float fr[C2N];
    int n = blockIdx.x, t = threadIdx.x;
    if (t < C2N) fr[t] = f_raw[n * C2N + t];
    __syncthreads();
    float acc = fcb[t];
#pragma unroll
    for (int c = 0; c < C2N; c++) acc += fr[c] * fcw[c * DD + t];
    f[n * DD + t] = fmaxf(acc, 0.f);
}

__global__ __launch_bounds__(128) void fafb_k(const float* __restrict__ f,
        const float* __restrict__ Wa, const float* __restrict__ Wb,
        float* __restrict__ fa, float* __restrict__ fb) {
    __shared__ float fr[DD];
    int n = blockIdx.x, t = threadIdx.x;
    fr[t] = f[n * DD + t];
    __syncthreads();
    float a = 0.f, b = 0.f;
    for (int k = 0; k < DD; k++) {
        float fv = fr[k];
        a += fv * Wa[k * HE + t];
        b += fv * Wb[k * HE + t];
    }
    fa[n * HE + t] = a;
    fb[n * HE + t] = b;
}

// ---------------- stage 2: edge MLP + gumbel hard mask (unchanged) ----------
__global__ __launch_bounds__(256) void edge_mask(const float* __restrict__ fa,
        const float* __restrict__ fb, const float* __restrict__ b1,
        const float* __restrict__ W2, const float* __restrict__ b2,
        const float* __restrict__ u_noise, float* __restrict__ mask) {
    __shared__ float sfa[16][129], sfb[16][129];
    __shared__ float w20[HE], w21[HE], b1s[HE];
    __shared__ float b2s[2];
    int t = threadIdx.x;
    int i0 = blockIdx.x * 16, j0 = blockIdx.y * 16;
    for (int idx = t; idx < 16 * HE; idx += 256) {
        int r = idx >> 7, c = idx & 127;
        sfa[r][c] = (i0 + r < NN) ? fa[(i0 + r) * HE + c] : 0.f;
        sfb[r][c] = (j0 + r < NN) ? fb[(j0 + r) * HE + c] : 0.f;
    }
    if (t < HE) { w20[t] = W2[t * 2]; w21[t] = W2[t * 2 + 1]; b1s[t] = b1[t]; }
    if (t < 2) b2s[t] = b2[t];
    __syncthreads();
    int ti = t >> 4, tj = t & 15;
    int i = i0 + ti, j = j0 + tj;
    if (i >= NN || j >= NN) return;
    double l0 = 0.0, l1 = 0.0;
    for (int dd = 0; dd < HE; dd++) {
        float hv = fmaxf(sfa[ti][dd] + sfb[tj][dd] + b1s[dd], 0.f);
        l0 += (double)hv * (double)w20[dd];
        l1 += (double)hv * (double)w21[dd];
    }
    long e = (long)i * NN + j;
    double u0 = (double)u_noise[2 * e], u1 = (double)u_noise[2 * e + 1];
    double g0 = -log(-log(u0 + 1e-10) + 1e-10);
    double g1 = -log(-log(u1 + 1e-10) + 1e-10);
    double s0 = l0 + (double)b2s[0] + g0;
    double s1 = l1 + (double)b2s[1] + g1;
    float mv = (i == j) ? 0.f : ((s0 >= s1) ? 1.f : 0.f);
    mask[e] = mv;
}

__global__ __launch_bounds__(256) void row_deg(const float* __restrict__ mask,
        float* __restrict__ deg) {
    __shared__ float red[256];
    int i = blockIdx.x, t = threadIdx.x;
    float s = 0.f;
    for (int j = t; j < NN; j += 256) s += mask[i * NN + j];
    red[t] = s;
    __syncthreads();
    for (int w = 128; w > 0; w >>= 1) {
        if (t < w) red[t] += red[t + w];
        __syncthreads();
    }
    if (t == 0) deg[i] = red[0];
}

// A (bf16, zero-padded 1024x1024)
__global__ __launch_bounds__(256) void make_A(const float* __restrict__ mask,
        const float* __restrict__ deg, __bf16* __restrict__ A_bf) {
    int idx = blockIdx.x * 256 + threadIdx.x;
    int i = idx >> 10, j = idx & 1023;
    float v = 0.f;
    if (i < NN && j < NN) v = mask[i * NN + j] / (deg[i] + 1e-6f);
    A_bf[idx] = (__bf16)v;
}

__global__ void init_zero(float* __restrict__ a, int na, float* __restrict__ b, int nb) {
    int stride = gridDim.x * blockDim.x;
    for (int i = blockIdx.x * blockDim.x + threadIdx.x; i < na; i += stride) a[i] = 0.f;
    for (int i = blockIdx.x * blockDim.x + threadIdx.x; i < nb; i += stride) b[i] = 0.f;
}

// ---------------- weight prep: bf16 transposed gate weights ----------------
__global__ __launch_bounds__(256) void prep_w(
        const float* __restrict__ eWru0, const float* __restrict__ eWru1,
        const float* __restrict__ eWc0,  const float* __restrict__ eWc1,
        const float* __restrict__ dWru0, const float* __restrict__ dWru1,
        const float* __restrict__ dWc0,  const float* __restrict__ dWc1,
        __bf16* __restrict__ wp) {
    int idx = blockIdx.x * 256 + threadIdx.x;
    if (idx >= 49152) return;
    int half = idx / 24576;              // 0 enc, 1 dec
    int li = idx - half * 24576;
    const float* Wru0 = half ? dWru0 : eWru0;
    const float* Wru1 = half ? dWru1 : eWru1;
    const float* Wc0  = half ? dWc0  : eWc0;
    const float* Wc1  = half ? dWc1  : eWc1;
    float v;
    if (li < 16384) {
        const float* W = (li < 8192) ? Wru0 : Wru1;
        int l2 = li & 8191;
        int d = l2 >> 6, f = l2 & 63;
        v = W[(1 + f) * 128 + d];
    } else {
        int l2 = li - 16384;
        const float* W = (l2 < 4096) ? Wc0 : Wc1;
        int l3 = l2 & 4095;
        int d = l3 >> 6, f = l3 & 63;
        v = W[(1 + f) * 64 + d];
    }
    wp[idx] = (__bf16)v;
}

// ---------------- x fill (step 0) ----------------
__global__ __launch_bounds__(256) void xfill0(const float* __restrict__ inputs,
        __bf16* __restrict__ xT) {
    int idx = blockIdx.x * 256 + threadIdx.x;   // 16384
    int b = idx >> 10, j = idx & 1023;
    float v = (j < NN) ? inputs[(b * SS + 0) * NN + j] : 0.f;
    xT[b * 1024 + j] = (__bf16)v;
}

// ---------------- bf16 MFMA GEMM: C[1024 x cstride] = A[1024x1024] @ B ------
// B given transposed: BT[c][k] rows c (64 per tile); tile==nbt uses xT[64x1024].
__global__ __launch_bounds__(256) void gemm_bf(const __bf16* __restrict__ A,
        const __bf16* __restrict__ BT, const __bf16* __restrict__ xT,
        float* __restrict__ C, int cstride, int nbt) {
    __shared__ __align__(16) __bf16 As[2][2048];
    __shared__ __align__(16) __bf16 Bs[2][2048];
    int t = threadIdx.x;
    int bm = blockIdx.x * 64;
    int tile = blockIdx.y;
    const __bf16* Bbase = (tile < nbt) ? (BT + tile * 65536) : xT;
    int am = t >> 2;
    int ag = ((t & 3) - (am >> 1)) & 3;          // chunk swizzle
    const __bf16* agp = A + (bm + am) * 1024 + ag * 8;
    const __bf16* bgp = Bbase + am * 1024 + ag * 8;
    int w = t >> 6, l = t & 63, lr = l & 15, lh = l >> 4;
    int ldso = t * 8;
    f32x4 acc[4];
#pragma unroll
    for (int i = 0; i < 4; i++) acc[i] = (f32x4){0.f, 0.f, 0.f, 0.f};

    glds16(agp, &As[0][ldso]);
    glds16(bgp, &Bs[0][ldso]);
    __syncthreads();
    int cur = 0;
    for (int it = 0; it < 32; ++it) {
        if (it < 31) {
            glds16(agp + (it + 1) * 32, &As[cur ^ 1][ldso]);
            glds16(bgp + (it + 1) * 32, &Bs[cur ^ 1][ldso]);
        }
        int arow = w * 16 + lr;
        int asw = (lh + (arow >> 1)) & 3;
        bf16x8 af = *(const bf16x8*)&As[cur][arow * 32 + asw * 8];
#pragma unroll
        for (int ct = 0; ct < 4; ++ct) {
            int nrow = ct * 16 + lr;
            int bsw = (lh + (nrow >> 1)) & 3;
            bf16x8 bv = *(const bf16x8*)&Bs[cur][nrow * 32 + bsw * 8];
            acc[ct] = __builtin_amdgcn_mfma_f32_16x16x32_bf16(af, bv, acc[ct], 0, 0, 0);
        }
        __syncthreads();
        cur ^= 1;
    }
#pragma unroll
    for (int ct = 0; ct < 4; ++ct)
#pragma unroll
        for (int r = 0; r < 4; ++r) {
            int m_loc = w * 16 + lh * 4 + r;
            C[(bm + m_loc) * cstride + tile * 64 + ct * 16 + lr] = acc[ct][r];
        }
}

// ---------------- gate1 (r,u): MFMA M=16384,N=128,K=128 + fused epilogue ----
__global__ __launch_bounds__(256) void gate1(const float* __restrict__ h32,
        const float* __restrict__ agg, const __bf16* __restrict__ W0T,
        const __bf16* __restrict__ W1T, const float* __restrict__ Wru0,
        const float* __restrict__ Wru1, const float* __restrict__ bru,
        const __bf16* __restrict__ xT, __bf16* __restrict__ RHb,
        __bf16* __restrict__ RHbT, float* __restrict__ ubuf) {
    __shared__ __align__(16) __bf16 Ah[64 * 72];
    __shared__ __align__(16) __bf16 Ag[64 * 72];
    __shared__ __align__(16) __bf16 Wt0[128 * 72];
    __shared__ __align__(16) __bf16 Wt1[128 * 72];
    __shared__ float xs[64], axs[64], w0x[128], w1x[128], bbs[128];
    int t = threadIdx.x;
    int m0 = blockIdx.x * 64;
    {
        int m = t >> 2, c4 = t & 3;
        int mg = m0 + m;
        const float* hp = h32 + mg * 64 + c4 * 16;
        float4 v0 = *(const float4*)(hp), v1 = *(const float4*)(hp + 4);
        float4 v2 = *(const float4*)(hp + 8), v3 = *(const float4*)(hp + 12);
        *(bf16x8*)&Ah[m * 72 + c4 * 16] = pack8(v0, v1);
        *(bf16x8*)&Ah[m * 72 + c4 * 16 + 8] = pack8(v2, v3);
        const float* ap = agg + (mg >> 4) * 1088 + (mg & 15) * 64 + c4 * 16;
        v0 = *(const float4*)(ap); v1 = *(const float4*)(ap + 4);
        v2 = *(const float4*)(ap + 8); v3 = *(const float4*)(ap + 12);
        *(bf16x8*)&Ag[m * 72 + c4 * 16] = pack8(v0, v1);
        *(bf16x8*)&Ag[m * 72 + c4 * 16 + 8] = pack8(v2, v3);
    }
    for (int i = t; i < 128 * 8; i += 256) {
        int n = i >> 3, c2 = i & 7;
        *(bf16x8*)&Wt0[n * 72 + c2 * 8] = *(const bf16x8*)&W0T[n * 64 + c2 * 8];
        *(bf16x8*)&Wt1[n * 72 + c2 * 8] = *(const bf16x8*)&W1T[n * 64 + c2 * 8];
    }
    if (t < 64) {
        int mg = m0 + t;
        xs[t] = (float)xT[(mg & 15) * 1024 + (mg >> 4)];
        axs[t] = agg[(mg >> 4) * 1088 + 1024 + (mg & 15)];
    }
    if (t < 128) { w0x[t] = Wru0[t]; w1x[t] = Wru1[t]; bbs[t] = bru[t]; }
    __syncthreads();

    int w = t >> 6, l = t & 63, lr = l & 15, lh = l >> 4;
    f32x4 acc[8];
#pragma unroll
    for (int i = 0; i < 8; i++) acc[i] = (f32x4){0.f, 0.f, 0.f, 0.f};
    int arow = w * 16 + lr;
#pragma unroll
    for (int h2 = 0; h2 < 2; ++h2) {
        bf16x8 ah = *(const bf16x8*)&Ah[arow * 72 + h2 * 32 + lh * 8];
        bf16x8 ag = *(const bf16x8*)&Ag[arow * 72 + h2 * 32 + lh * 8];
#pragma unroll
        for (int ct = 0; ct < 8; ++ct) {
            int n = ct * 16 + lr;
            bf16x8 b0 = *(const bf16x8*)&Wt0[n * 72 + h2 * 32 + lh * 8];
            bf16x8 b1 = *(const bf16x8*)&Wt1[n * 72 + h2 * 32 + lh * 8];
            acc[ct] = __builtin_amdgcn_mfma_f32_16x16x32_bf16(ah, b0, acc[ct], 0, 0, 0);
            acc[ct] = __builtin_amdgcn_mfma_f32_16x16x32_bf16(ag, b1, acc[ct], 0, 0, 0);
        }
    }
#pragma unroll
    for (int ct = 0; ct < 8; ++ct) {
        int d = ct * 16 + lr;
#pragma unroll
        for (int r = 0; r < 4; ++r) {
            int m_loc = w * 16 + lh * 4 + r;
            int mg = m0 + m_loc;
            float pre = acc[ct][r] + xs[m_loc] * w0x[d] + axs[m_loc] * w1x[d] + bbs[d];
            float sg = 1.f / (1.f + expf(-pre));
            if (d < 64) {
                float hv = (float)Ah[m_loc * 72 + d];
                float rh = sg * hv;
                RHb[mg * 64 + d] = (__bf16)rh;
                RHbT[((mg & 15) * 64 + d) * 1024 + (mg >> 4)] = (__bf16)rh;
            } else {
                ubuf[mg * 64 + (d - 64)] = sg;
            }
        }
    }
}

// ---------------- gate2 (c + state update): MFMA M=16384,N=64,K=128 ---------
__global__ __launch_bounds__(256) void gate2(const __bf16* __restrict__ RHb,
        const float* __restrict__ agg2, const __bf16* __restrict__ WcT0,
        const __bf16* __restrict__ WcT1, const float* __restrict__ Wc0,
        const float* __restrict__ Wc1, const float* __restrict__ bc,
        __bf16* __restrict__ xT, const float* __restrict__ ubuf,
        float* __restrict__ h32, __bf16* __restrict__ HbT,
        const float* __restrict__ agg, const float* __restrict__ inputs,
        int mode, int s1) {
    __shared__ __align__(16) __bf16 Ah[64 * 72];
    __shared__ __align__(16) __bf16 Ag[64 * 72];
    __shared__ __align__(16) __bf16 Wt0[64 * 72];
    __shared__ __align__(16) __bf16 Wt1[64 * 72];
    __shared__ float xs[64], axs[64], w0x[64], w1x[64], bbs[64];
    int t = threadIdx.x;
    int m0 = blockIdx.x * 64;
    {
        int m = t >> 2, c4 = t & 3;
        int mg = m0 + m;
        const __bf16* rp = RHb + mg * 64 + c4 * 16;
        *(bf16x8*)&Ah[m * 72 + c4 * 16] = *(const bf16x8*)(rp);
        *(bf16x8*)&Ah[m * 72 + c4 * 16 + 8] = *(const bf16x8*)(rp + 8);
        const float* ap = agg2 + mg * 64 + c4 * 16;
        float4 v0 = *(const float4*)(ap), v1 = *(const float4*)(ap + 4);
        float4 v2 = *(const float4*)(ap + 8), v3 = *(const float4*)(ap + 12);
        *(bf16x8*)&Ag[m * 72 + c4 * 16] = pack8(v0, v1);
        *(bf16x8*)&Ag[m * 72 + c4 * 16 + 8] = pack8(v2, v3);
    }
    for (int i = t; i < 64 * 8; i += 256) {
        int n = i >> 3, c2 = i & 7;
        *(bf16x8*)&Wt0[n * 72 + c2 * 8] = *(const bf16x8*)&WcT0[n * 64 + c2 * 8];
        *(bf16x8*)&Wt1[n * 72 + c2 * 8] = *(const bf16x8*)&WcT1[n * 64 + c2 * 8];
    }
    if (t < 64) {
        int mg = m0 + t;
        xs[t] = (float)xT[(mg & 15) * 1024 + (mg >> 4)];
        axs[t] = agg[(mg >> 4) * 1088 + 1024 + (mg & 15)];
        w0x[t] = Wc0[t]; w1x[t] = Wc1[t]; bbs[t] = bc[t];
    }
    __syncthreads();

    int w = t >> 6, l = t & 63, lr = l & 15, lh = l >> 4;
    f32x4 acc[4];
#pragma unroll
    for (int i = 0; i < 4; i++) acc[i] = (f32x4){0.f, 0.f, 0.f, 0.f};
    int arow = w * 16 + lr;
#pragma unroll
    for (int h2 = 0; h2 < 2; ++h2) {
        bf16x8 ah = *(const bf16x8*)&Ah[arow * 72 + h2 * 32 + lh * 8];
        bf16x8 ag = *(const bf16x8*)&Ag[arow * 72 + h2 * 32 + lh * 8];
#pragma unroll
        for (int ct = 0; ct < 4; ++ct) {
            int n = ct * 16 + lr;
            bf16x8 b0 = *(const bf16x8*)&Wt0[n * 72 + h2 * 32 + lh * 8];
            bf16x8 b1 = *(const bf16x8*)&Wt1[n * 72 + h2 * 32 + lh * 8];
            acc[ct] = __builtin_amdgcn_mfma_f32_16x16x32_bf16(ah, b0, acc[ct], 0, 0, 0);
            acc[ct] = __builtin_amdgcn_mfma_f32_16x16x32_bf16(ag, b1, acc[ct], 0, 0, 0);
        }
    }
#pragma unroll
    for (int ct = 0; ct < 4; ++ct) {
        int d = ct * 16 + lr;
#pragma unroll
        for (int r = 0; r < 4; ++r) {
            int m_loc = w * 16 + lh * 4 + r;
            int mg = m0 + m_loc;
            float pre = acc[ct][r] + xs[m_loc] * w0x[d] + axs[m_loc] * w1x[d] + bbs[d];
            float cv = tanhf(pre);
            float u = ubuf[mg * 64 + d];
            float hold = h32[mg * 64 + d];
            float hn = u * hold + (1.f - u) * cv;
            h32[mg * 64 + d] = hn;
            HbT[((mg & 15) * 64 + d) * 1024 + (mg >> 4)] = (__bf16)hn;
            if (mode <= 1 && d == 0) {
                int b = mg & 15, j = mg >> 4;
                float xv = 0.f;
                if (mode == 0 && j < NN) xv = inputs[(b * SS + s1) * NN + j];
                xT[b * 1024 + j] = (__bf16)xv;
            }
        }
    }
}

// ---------------- decoder projection ----------------
__global__ __launch_bounds__(256) void proj_k(const float* __restrict__ h32,
        const float* __restrict__ projw, const float* __restrict__ projb,
        float* __restrict__ outputs, __bf16* __restrict__ xT, int hs) {
    __shared__ float pw[64];
    int t = threadIdx.x;
    if (t < 64) pw[t] = projw[t];
    __syncthreads();
    int m = blockIdx.x * 256 + t;
    const float* hp = h32 + m * 64;
    float acc = 0.f;
#pragma unroll
    for (int f = 0; f < 64; f += 4) {
        float4 v = *(const float4*)(hp + f);
        acc += v.x * pw[f] + v.y * pw[f + 1] + v.z * pw[f + 2] + v.w * pw[f + 3];
    }
    float yo = acc + projb[0];
    int j = m >> 4, b = m & 15;
    xT[b * 1024 + j] = (__bf16)yo;
    if (j < NN) outputs[(b * HH + hs) * NN + j] = yo;
}

// ---------------- loss ----------------
__global__ __launch_bounds__(256) void loss1(const float* __restrict__ outs,
        const float* __restrict__ tgt, float* __restrict__ part) {
    __shared__ float red[256];
    int t = blockIdx.x * 256 + threadIdx.x;
    float s = 0.f;
    for (int i = t; i < BB * HH * NN; i += 256 * 256) {
        float dd = outs[i] - tgt[i];
        s += dd * dd;
    }
    red[threadIdx.x] = s;
    __syncthreads();
    for (int w = 128; w > 0; w >>= 1) {
        if (threadIdx.x < w) red[threadIdx.x] += red[threadIdx.x + w];
        __syncthreads();
    }
    if (threadIdx.x == 0) part[blockIdx.x] = red[0];
}

__global__ __launch_bounds__(256) void loss2(const float* __restrict__ part,
        float* __restrict__ loss) {
    __shared__ double red[256];
    int t = threadIdx.x;
    red[t] = (double)part[t];
    __syncthreads();
    for (int w = 128; w > 0; w >>= 1) {
        if (t < w) red[t] += red[t + w];
        __syncthreads();
    }
    if (t == 0) loss[0] = (float)(red[0] / (double)(BB * HH * NN));
}

// ---------------- host ----------------
extern "C" void kernel_launch(void* const* d_in, const int* in_sizes, int n_in,
                              void* d_out, int out_size, void* d_ws, size_t ws_size,
                              hipStream_t stream) {
    const float* inputs  = (const float*)d_in[0];
    const float* ein     = (const float*)d_in[1];
    const float* targets = (const float*)d_in[2];
    const float* u_noise = (const float*)d_in[3];
    const float* c1w = (const float*)d_in[4];
    const float* c1b = (const float*)d_in[5];
    const float* c2w = (const float*)d_in[6];
    const float* c2b = (const float*)d_in[7];
    const float* fcw = (const float*)d_in[8];
    const float* fcb = (const float*)d_in[9];
    const float* Wa  = (const float*)d_in[10];
    const float* Wb  = (const float*)d_in[11];
    const float* b1  = (const float*)d_in[12];
    const float* W2  = (const float*)d_in[13];
    const float* b2  = (const float*)d_in[14];
    const float* eWru0 = (const float*)d_in[15];
    const float* eWru1 = (const float*)d_in[16];
    const float* ebru  = (const float*)d_in[17];
    const float* eWc0  = (const float*)d_in[18];
    const float* eWc1  = (const float*)d_in[19];
    const float* ebc   = (const float*)d_in[20];
    const float* dWru0 = (const float*)d_in[21];
    const float* dWru1 = (const float*)d_in[22];
    const float* dbru  = (const float*)d_in[23];
    const float* dWc0  = (const float*)d_in[24];
    const float* dWc1  = (const float*)d_in[25];
    const float* dbc   = (const float*)d_in[26];
    const float* projw = (const float*)d_in[27];
    const float* projb = (const float*)d_in[28];

    float* out = (float*)d_out;
    float* mask    = out;
    float* outputs = out + NN * NN;
    float* loss    = out + NN * NN + BB * HH * NN;

    float* ws = (float*)d_ws;
    float* f_raw = ws;                       // 16,000
    float* fbuf  = ws + 16000;               // 128,000
    float* fa    = ws + 144000;
    float* fb    = ws + 272000;
    float* deg   = ws + 400000;              // 1,024
    float* lossp = ws + 401024;              // 256
    float* agg   = ws + 401280;              // 1024*1088
    float* agg2  = ws + 1515392;             // 1024*1024
    float* h32   = ws + 2563968;             // 16384*64
    float* ubuf  = ws + 3612544;             // 16384*64
    __bf16* A_bf  = (__bf16*)(ws + 4661120); // 1024*1024
    __bf16* HbT   = (__bf16*)(ws + 5185408); // 1024*1024
    __bf16* RHbT  = (__bf16*)(ws + 5709696); // 1024*1024
    __bf16* RHb   = (__bf16*)(ws + 6233984); // 16384*64
    __bf16* xT    = (__bf16*)(ws + 6758272); // 64*1024
    __bf16* wp    = (__bf16*)(ws + 6791040); // 49,152
    __bf16* eW0T = wp, *eW1T = wp + 8192, *eWc0T = wp + 16384, *eWc1T = wp + 20480;
    __bf16* dW0T = wp + 24576, *dW1T = wp + 32768, *dWc0T = wp + 40960, *dWc1T = wp + 45056;

    // zero: h32 (fp32) and HbT (bf16, 524288 floats' worth)
    init_zero<<<2048, 256, 0, stream>>>(h32, 16384 * 64, ws + 5185408, 524288);
    prep_w<<<192, 256, 0, stream>>>(eWru0, eWru1, eWc0, eWc1, dWru0, dWru1, dWc0, dWc1, wp);
    xfill0<<<64, 256, 0, stream>>>(inputs, xT);

    // graph head
    s1_conv<<<NN, 256, 0, stream>>>(ein, c1w, c1b, c2w, c2b, f_raw);
    fc_relu<<<NN, 128, 0, stream>>>(f_raw, fcw, fcb, fbuf);
    fafb_k<<<NN, 128, 0, stream>>>(fbuf, Wa, Wb, fa, fb);
    edge_mask<<<dim3(63, 63), 256, 0, stream>>>(fa, fb, b1, W2, b2, u_noise, mask);
    row_deg<<<NN, 256, 0, stream>>>(mask, deg);
    make_A<<<4096, 256, 0, stream>>>(mask, deg, A_bf);

    // encoder
    for (int s = 0; s < SS; s++) {
        gemm_bf<<<dim3(16, 17), 256, 0, stream>>>(A_bf, HbT, xT, agg, 1088, 16);
        gate1<<<256, 256, 0, stream>>>(h32, agg, eW0T, eW1T, eWru0, eWru1, ebru,
                                       xT, RHb, RHbT, ubuf);
        gemm_bf<<<dim3(16, 16), 256, 0, stream>>>(A_bf, RHbT, xT, agg2, 1024, 16);
        int mode = (s == SS - 1) ? 1 : 0;
        gate2<<<256, 256, 0, stream>>>(RHb, agg2, eWc0T, eWc1T, eWc0, eWc1, ebc,
                                       xT, ubuf, h32, HbT, agg, inputs, mode, s + 1);
    }
    // decoder
    for (int k = 0; k < HH; k++) {
        gemm_bf<<<dim3(16, 17), 256, 0, stream>>>(A_bf, HbT, xT, agg, 1088, 16);
        gate1<<<256, 256, 0, stream>>>(h32, agg, dW0T, dW1T, dWru0, dWru1, dbru,
                                       xT, RHb, RHbT, ubuf);
        gemm_bf<<<dim3(16, 16), 256, 0, stream>>>(A_bf, RHbT, xT, agg2, 1024, 16);
        gate2<<<256, 256, 0, stream>>>(RHb, agg2, dWc0T, dWc1T, dWc0, dWc1, dbc,
                                       xT, ubuf, h32, HbT, agg, inputs, 2, 0);
        proj_k<<<64, 256, 0, stream>>>(h32, projw, projb, outputs, xT, k);
    }

    loss1<<<256, 256, 0, stream>>>(outputs, targets, lossp);
    loss2<<<1, 256, 0, stream>>>(lossp, loss);
}

// Round 3
// 1357.438 us; speedup vs baseline: 3.8477x; 1.4442x over previous
//
#include <hip/hip_runtime.h>
#include <math.h>

// ---------------- problem constants ----------------
#define NN      1000
#define TLEN    4000
#define BB      16
#define SS      12
#define HH      12
#define HID     64
#define C1N     8
#define C2N     16
#define KW      10
#define L1LEN   3991
#define L2LEN   3982
#define DD      128
#define HE      128

typedef __bf16 bf16x8 __attribute__((ext_vector_type(8)));
typedef float  f32x4  __attribute__((ext_vector_type(4)));
typedef float  f32x2  __attribute__((ext_vector_type(2)));
typedef __attribute__((address_space(3))) unsigned int       as3_u32;
typedef const __attribute__((address_space(1))) unsigned int as1_u32;

__device__ __forceinline__ void glds16(const void* g, void* l) {
    __builtin_amdgcn_global_load_lds((as1_u32*)g, (as3_u32*)l, 16, 0, 0);
}

__device__ __forceinline__ bf16x8 pack8(float4 a, float4 b) {
    bf16x8 r;
    r[0] = (__bf16)a.x; r[1] = (__bf16)a.y; r[2] = (__bf16)a.z; r[3] = (__bf16)a.w;
    r[4] = (__bf16)b.x; r[5] = (__bf16)b.y; r[6] = (__bf16)b.z; r[7] = (__bf16)b.w;
    return r;
}

// ---------------- stage 1: fused conv1+conv2+pool (packed f32x2 FMA) --------
#define TT 512
__global__ __launch_bounds__(256) void s1_conv(const float* __restrict__ ein,
        const float* __restrict__ w1, const float* __restrict__ b1c,
        const float* __restrict__ w2, const float* __restrict__ b2c,
        float* __restrict__ f_raw) {
    __shared__ float xb[TLEN];
    __shared__ float c1t[C1N][TT + KW];
    __shared__ float w1s[C1N * KW];
    __shared__ __align__(16) float w2s[C1N * KW * C2N];   // [c1][k][c2]
    __shared__ float b1s[C1N], b2s[C2N];
    __shared__ float red[256];
    int n = blockIdx.x, t = threadIdx.x;
    for (int i = t; i < TLEN; i += 256) xb[i] = ein[n * TLEN + i];
    for (int i = t; i < C1N * KW; i += 256) w1s[i] = w1[i];
    for (int i = t; i < C1N * KW * C2N; i += 256) {
        int c2 = i & 15, c1k = i >> 4;
        w2s[i] = w2[c2 * (C1N * KW) + c1k];
    }
    if (t < C1N) b1s[t] = b1c[t];
    if (t < C2N) b2s[t] = b2c[t];
    float pool[C2N];
#pragma unroll
    for (int c = 0; c < C2N; c++) pool[c] = 0.f;
    __syncthreads();

    for (int t0 = 0; t0 < L2LEN; t0 += TT) {
        int c1len = min(TT + KW - 1, L1LEN - t0);
        for (int c = 0; c < C1N; c++) {
            for (int p = t; p < c1len; p += 256) {
                float acc = b1s[c];
#pragma unroll
                for (int k = 0; k < KW; k++) acc += xb[t0 + p + k] * w1s[c * KW + k];
                c1t[c][p] = fmaxf(acc, 0.f);
            }
        }
        __syncthreads();
        int q0 = t0 + t, q1 = t0 + t + 256;
        bool v0 = (q0 < L2LEN), v1 = (q1 < L2LEN) && (t + 256 < TT);
        if (v0 || v1) {
            f32x2 a[C2N];
#pragma unroll
            for (int c = 0; c < C2N; c++) a[c] = (f32x2){b2s[c], b2s[c]};
            int l0 = t, l1 = t + 256;
            for (int c1 = 0; c1 < C1N; c1++) {
#pragma unroll
                for (int k = 0; k < KW; k++) {
                    float x0 = v0 ? c1t[c1][l0 + k] : 0.f;
                    float x1 = v1 ? c1t[c1][l1 + k] : 0.f;
                    f32x2 x01 = {x0, x1};
                    const float4* wp4 = (const float4*)&w2s[(c1 * KW + k) * C2N];
                    float4 wa = wp4[0], wb2 = wp4[1], wc = wp4[2], wd = wp4[3];
                    a[0] += x01 * wa.x;  a[1] += x01 * wa.y;
                    a[2] += x01 * wa.z;  a[3] += x01 * wa.w;
                    a[4] += x01 * wb2.x; a[5] += x01 * wb2.y;
                    a[6] += x01 * wb2.z; a[7] += x01 * wb2.w;
                    a[8] += x01 * wc.x;  a[9] += x01 * wc.y;
                    a[10] += x01 * wc.z; a[11] += x01 * wc.w;
                    a[12] += x01 * wd.x; a[13] += x01 * wd.y;
                    a[14] += x01 * wd.z; a[15] += x01 * wd.w;
                }
            }
#pragma unroll
            for (int c2 = 0; c2 < C2N; c2++) {
                if (v0) pool[c2] += fmaxf(a[c2][0], 0.f);
                if (v1) pool[c2] += fmaxf(a[c2][1], 0.f);
            }
        }
        __syncthreads();
    }
    for (int c2 = 0; c2 < C2N; c2++) {
        red[t] = pool[c2];
        __syncthreads();
        for (int s = 128; s > 0; s >>= 1) {
            if (t < s) red[t] += red[t + s];
            __syncthreads();
        }
        if (t == 0) f_raw[n * C2N + c2] = red[0] / 3982.0f;
        __syncthreads();
    }
}

// ---------------- stage 1b/1c ----------------
__global__ __launch_bounds__(128) void fc_relu(const float* __restrict__ f_raw,
        const float* __restrict__ fcw, const float* __restrict__ fcb,
        float* __restrict__ f) {
    __shared__ float fr[C2N];
    int n = blockIdx.x, t = threadIdx.x;
    if (t < C2N) fr[t] = f_raw[n * C2N + t];
    __syncthreads();
    float acc = fcb[t];
#pragma unroll
    for (int c = 0; c < C2N; c++) acc += fr[c] * fcw[c * DD + t];
    f[n * DD + t] = fmaxf(acc, 0.f);
}

__global__ __launch_bounds__(128) void fafb_k(const float* __restrict__ f,
        const float* __restrict__ Wa, const float* __restrict__ Wb,
        float* __restrict__ fa, float* __restrict__ fb) {
    __shared__ float fr[DD];
    int n = blockIdx.x, t = threadIdx.x;
    fr[t] = f[n * DD + t];
    __syncthreads();
    float a = 0.f, b = 0.f;
    for (int k = 0; k < DD; k++) {
        float fv = fr[k];
        a += fv * Wa[k * HE + t];
        b += fv * Wb[k * HE + t];
    }
    fa[n * HE + t] = a;
    fb[n * HE + t] = b;
}

// ---------------- stage 2: edge MLP + gumbel hard mask (float4 LDS) ---------
__global__ __launch_bounds__(256) void edge_mask(const float* __restrict__ fa,
        const float* __restrict__ fb, const float* __restrict__ b1,
        const float* __restrict__ W2, const float* __restrict__ b2,
        const float* __restrict__ u_noise, float* __restrict__ mask) {
    __shared__ __align__(16) float sfa[16][132], sfb[16][132];
    __shared__ __align__(16) float w20[HE], w21[HE], b1s[HE];
    __shared__ float b2s[2];
    int t = threadIdx.x;
    int i0 = blockIdx.x * 16, j0 = blockIdx.y * 16;
    for (int idx = t; idx < 16 * HE; idx += 256) {
        int r = idx >> 7, c = idx & 127;
        sfa[r][c] = (i0 + r < NN) ? fa[(i0 + r) * HE + c] : 0.f;
        sfb[r][c] = (j0 + r < NN) ? fb[(j0 + r) * HE + c] : 0.f;
    }
    if (t < HE) { w20[t] = W2[t * 2]; w21[t] = W2[t * 2 + 1]; b1s[t] = b1[t]; }
    if (t < 2) b2s[t] = b2[t];
    __syncthreads();
    int ti = t >> 4, tj = t & 15;
    int i = i0 + ti, j = j0 + tj;
    if (i >= NN || j >= NN) return;
    double l0 = 0.0, l1 = 0.0;
    for (int dd = 0; dd < HE; dd += 4) {
        float4 av = *(const float4*)&sfa[ti][dd];
        float4 bv = *(const float4*)&sfb[tj][dd];
        float4 bb = *(const float4*)&b1s[dd];
        float4 w0 = *(const float4*)&w20[dd];
        float4 w1 = *(const float4*)&w21[dd];
        float h0 = fmaxf(av.x + bv.x + bb.x, 0.f);
        l0 += (double)h0 * (double)w0.x; l1 += (double)h0 * (double)w1.x;
        float h1 = fmaxf(av.y + bv.y + bb.y, 0.f);
        l0 += (double)h1 * (double)w0.y; l1 += (double)h1 * (double)w1.y;
        float h2 = fmaxf(av.z + bv.z + bb.z, 0.f);
        l0 += (double)h2 * (double)w0.z; l1 += (double)h2 * (double)w1.z;
        float h3 = fmaxf(av.w + bv.w + bb.w, 0.f);
        l0 += (double)h3 * (double)w0.w; l1 += (double)h3 * (double)w1.w;
    }
    long e = (long)i * NN + j;
    double u0 = (double)u_noise[2 * e], u1 = (double)u_noise[2 * e + 1];
    double g0 = -log(-log(u0 + 1e-10) + 1e-10);
    double g1 = -log(-log(u1 + 1e-10) + 1e-10);
    double s0 = l0 + (double)b2s[0] + g0;
    double s1 = l1 + (double)b2s[1] + g1;
    float mv = (i == j) ? 0.f : ((s0 >= s1) ? 1.f : 0.f);
    mask[e] = mv;
}

__global__ __launch_bounds__(256) void row_deg(const float* __restrict__ mask,
        float* __restrict__ deg) {
    __shared__ float red[256];
    int i = blockIdx.x, t = threadIdx.x;
    float s = 0.f;
    for (int j = t; j < NN; j += 256) s += mask[i * NN + j];
    red[t] = s;
    __syncthreads();
    for (int w = 128; w > 0; w >>= 1) {
        if (t < w) red[t] += red[t + w];
        __syncthreads();
    }
    if (t == 0) deg[i] = red[0];
}

__global__ __launch_bounds__(256) void make_A(const float* __restrict__ mask,
        const float* __restrict__ deg, __bf16* __restrict__ A_bf) {
    int idx = blockIdx.x * 256 + threadIdx.x;
    int i = idx >> 10, j = idx & 1023;
    float v = 0.f;
    if (i < NN && j < NN) v = mask[i * NN + j] / (deg[i] + 1e-6f);
    A_bf[idx] = (__bf16)v;
}

__global__ void init_zero(float* __restrict__ p, int n) {
    int stride = gridDim.x * blockDim.x;
    for (int i = blockIdx.x * blockDim.x + threadIdx.x; i < n; i += stride) p[i] = 0.f;
}

// ---------------- weight prep: bf16 transposed gate weights ----------------
__global__ __launch_bounds__(256) void prep_w(
        const float* __restrict__ eWru0, const float* __restrict__ eWru1,
        const float* __restrict__ eWc0,  const float* __restrict__ eWc1,
        const float* __restrict__ dWru0, const float* __restrict__ dWru1,
        const float* __restrict__ dWc0,  const float* __restrict__ dWc1,
        __bf16* __restrict__ wp) {
    int idx = blockIdx.x * 256 + threadIdx.x;
    if (idx >= 49152) return;
    int half = idx / 24576;
    int li = idx - half * 24576;
    const float* Wru0 = half ? dWru0 : eWru0;
    const float* Wru1 = half ? dWru1 : eWru1;
    const float* Wc0  = half ? dWc0  : eWc0;
    const float* Wc1  = half ? dWc1  : eWc1;
    float v;
    if (li < 16384) {
        const float* W = (li < 8192) ? Wru0 : Wru1;
        int l2 = li & 8191;
        int d = l2 >> 6, f = l2 & 63;
        v = W[(1 + f) * 128 + d];
    } else {
        int l2 = li - 16384;
        const float* W = (l2 < 4096) ? Wc0 : Wc1;
        int l3 = l2 & 4095;
        int d = l3 >> 6, f = l3 & 63;
        v = W[(1 + f) * 64 + d];
    }
    wp[idx] = (__bf16)v;
}

// XeT[(s*16+b)*1024 + j] = inputs[(b*SS+s)*NN + j]
__global__ __launch_bounds__(256) void prep_xe(const float* __restrict__ inputs,
        __bf16* __restrict__ XeT) {
    int idx = blockIdx.x * 256 + threadIdx.x;     // 192*1024
    int c = idx >> 10, j = idx & 1023;
    int s = c >> 4, b = c & 15;
    float v = (j < NN) ? inputs[(b * SS + s) * NN + j] : 0.f;
    XeT[c * 1024 + j] = (__bf16)v;
}

// ---------------- bf16 MFMA GEMM (small-N helper): C = A[1024x1024] @ BT^T --
__global__ __launch_bounds__(256) void gemm_bf(const __bf16* __restrict__ A,
        const __bf16* __restrict__ BT, float* __restrict__ C, int cstride) {
    __shared__ __align__(16) __bf16 As[2][2048];
    __shared__ __align__(16) __bf16 Bs[2][2048];
    int t = threadIdx.x;
    int bm = blockIdx.x * 64;
    int tile = blockIdx.y;
    const __bf16* Bbase = BT + tile * 65536;
    int am = t >> 2;
    int ag = ((t & 3) - (am >> 1)) & 3;
    const __bf16* agp = A + (bm + am) * 1024 + ag * 8;
    const __bf16* bgp = Bbase + am * 1024 + ag * 8;
    int w = t >> 6, l = t & 63, lr = l & 15, lh = l >> 4;
    int ldso = t * 8;
    f32x4 acc[4];
#pragma unroll
    for (int i = 0; i < 4; i++) acc[i] = (f32x4){0.f, 0.f, 0.f, 0.f};

    glds16(agp, &As[0][ldso]);
    glds16(bgp, &Bs[0][ldso]);
    __syncthreads();
    int cur = 0;
    for (int it = 0; it < 32; ++it) {
        if (it < 31) {
            glds16(agp + (it + 1) * 32, &As[cur ^ 1][ldso]);
            glds16(bgp + (it + 1) * 32, &Bs[cur ^ 1][ldso]);
        }
        int arow = w * 16 + lr;
        int asw = (lh + (arow >> 1)) & 3;
        bf16x8 af = *(const bf16x8*)&As[cur][arow * 32 + asw * 8];
#pragma unroll
        for (int ct = 0; ct < 4; ++ct) {
            int nrow = ct * 16 + lr;
            int bsw = (lh + (nrow >> 1)) & 3;
            bf16x8 bv = *(const bf16x8*)&Bs[cur][nrow * 32 + bsw * 8];
            acc[ct] = __builtin_amdgcn_mfma_f32_16x16x32_bf16(af, bv, acc[ct], 0, 0, 0);
        }
        __syncthreads();
        cur ^= 1;
    }
#pragma unroll
    for (int ct = 0; ct < 4; ++ct)
#pragma unroll
        for (int r = 0; r < 4; ++r) {
            int m_loc = w * 16 + lh * 4 + r;
            C[(bm + m_loc) * cstride + tile * 64 + ct * 16 + lr] = acc[ct][r];
        }
}

// ---------------- FG1: fused agg-GEMM + r/u gate --------------------------
// block (jblock, b): 64 j-rows, one batch. 512 threads = 8 waves.
__global__ __launch_bounds__(512) void fg1(const __bf16* __restrict__ A,
        const __bf16* __restrict__ HbT, const float* __restrict__ h32,
        const __bf16* __restrict__ W0T, const __bf16* __restrict__ W1T,
        const float* __restrict__ Wru0, const float* __restrict__ Wru1,
        const float* __restrict__ bru,
        const float* __restrict__ xsrc, int xstride,
        const float* __restrict__ aggX, int axstride, int axoff,
        __bf16* __restrict__ RHb, __bf16* __restrict__ RHbT,
        float* __restrict__ ubuf) {
    __shared__ __align__(16) __bf16 As[2][2048];
    __shared__ __align__(16) __bf16 Bs[2][2048];
    __shared__ __align__(16) __bf16 Ag[64 * 64];       // swizzled
    __shared__ __align__(16) __bf16 Wt0[128 * 64];     // swizzled
    __shared__ __align__(16) __bf16 Wt1[128 * 64];
    __shared__ float xs[64], axs[64], w0x[128], w1x[128], bbs[128];
    int t = threadIdx.x;
    int bm = blockIdx.x * 64;      // j block
    int b  = blockIdx.y;           // batch

    // stage gate weights (swizzled: slot seg' = (seg+n)&7)
    for (int i = t; i < 128 * 8; i += 512) {
        int n = i >> 3, seg = i & 7;
        int dst = n * 64 + (((seg + n) & 7) << 3);
        *(bf16x8*)&Wt0[dst] = *(const bf16x8*)&W0T[n * 64 + seg * 8];
        *(bf16x8*)&Wt1[dst] = *(const bf16x8*)&W1T[n * 64 + seg * 8];
    }
    if (t < 64) {
        int j = bm + t;
        xs[t] = (j < NN) ? xsrc[b * xstride + j] : 0.f;
        axs[t] = aggX[j * axstride + axoff + b];
    } else if (t < 192) {
        int d = t - 64;
        w0x[d] = Wru0[d]; w1x[d] = Wru1[d]; bbs[d] = bru[d];
    }

    // ---- main K=1024 MFMA loop: agg chunk = A[bm.., :] @ HbT[b*64.., :]^T --
    int half = t >> 8, tl = t & 255;
    int am = tl >> 2;
    int ag = ((tl & 3) - (am >> 1)) & 3;
    const __bf16* gp = half ? (HbT + (size_t)(b * 64 + am) * 1024 + ag * 8)
                            : (A + (size_t)(bm + am) * 1024 + ag * 8);
    int ldso = tl * 8;
    int w = t >> 6, l = t & 63, lr = l & 15, lh = l >> 4;
    int wr = w & 3, wc = w >> 2;
    f32x4 acc[2];
    acc[0] = (f32x4){0.f, 0.f, 0.f, 0.f};
    acc[1] = (f32x4){0.f, 0.f, 0.f, 0.f};

    if (half) glds16(gp, &Bs[0][ldso]); else glds16(gp, &As[0][ldso]);
    __syncthreads();
    int cur = 0;
    for (int it = 0; it < 32; ++it) {
        if (it < 31) {
            if (half) glds16(gp + (it + 1) * 32, &Bs[cur ^ 1][ldso]);
            else      glds16(gp + (it + 1) * 32, &As[cur ^ 1][ldso]);
        }
        int arow = wr * 16 + lr;
        int asw = (lh + (arow >> 1)) & 3;
        bf16x8 af = *(const bf16x8*)&As[cur][arow * 32 + asw * 8];
#pragma unroll
        for (int ct = 0; ct < 2; ++ct) {
            int nrow = wc * 32 + ct * 16 + lr;
            int bsw = (lh + (nrow >> 1)) & 3;
            bf16x8 bv = *(const bf16x8*)&Bs[cur][nrow * 32 + bsw * 8];
            acc[ct] = __builtin_amdgcn_mfma_f32_16x16x32_bf16(af, bv, acc[ct], 0, 0, 0);
        }
        __syncthreads();
        cur ^= 1;
    }

    // scatter agg chunk to LDS (bf16, swizzled)
#pragma unroll
    for (int ct = 0; ct < 2; ++ct)
#pragma unroll
        for (int r = 0; r < 4; ++r) {
            int m = wr * 16 + lh * 4 + r;
            int d = wc * 32 + ct * 16 + lr;
            Ag[m * 64 + ((((d >> 3) + m) & 7) << 3) + (d & 7)] = (__bf16)acc[ct][r];
        }
    __syncthreads();

    // ---- gate GEMM: [64 m] x [128 d], K = 64(h) + 64(agg) ----
    f32x4 g[4];
#pragma unroll
    for (int i = 0; i < 4; i++) g[i] = (f32x4){0.f, 0.f, 0.f, 0.f};
    int arow2 = wr * 16 + lr;
    const float* hrow = h32 + ((size_t)((bm + arow2) * 16 + b)) * 64;
#pragma unroll
    for (int h2 = 0; h2 < 2; ++h2) {
        float4 hv0 = *(const float4*)(hrow + h2 * 32 + lh * 8);
        float4 hv1 = *(const float4*)(hrow + h2 * 32 + lh * 8 + 4);
        bf16x8 ah = pack8(hv0, hv1);
        int sega = h2 * 4 + lh;
        bf16x8 agf = *(const bf16x8*)&Ag[arow2 * 64 + (((sega + arow2) & 7) << 3)];
#pragma unroll
        for (int ct = 0; ct < 4; ++ct) {
            int n = wc * 64 + ct * 16 + lr;
            int slot = n * 64 + (((sega + n) & 7) << 3);
            g[ct] = __builtin_amdgcn_mfma_f32_16x16x32_bf16(ah, *(const bf16x8*)&Wt0[slot], g[ct], 0, 0, 0);
            g[ct] = __builtin_amdgcn_mfma_f32_16x16x32_bf16(agf, *(const bf16x8*)&Wt1[slot], g[ct], 0, 0, 0);
        }
    }

    // ---- epilogue: sigmoid; d<64 -> r*h, d>=64 -> u ----
#pragma unroll
    for (int ct = 0; ct < 4; ++ct) {
        int d = wc * 64 + ct * 16 + lr;
#pragma unroll
        for (int r = 0; r < 4; ++r) {
            int m = wr * 16 + lh * 4 + r;
            int j = bm + m;
            size_t mg = (size_t)(j * 16 + b);
            float pre = g[ct][r] + xs[m] * w0x[d] + axs[m] * w1x[d] + bbs[d];
            float sg = 1.f / (1.f + expf(-pre));
            if (d < 64) {
                float hv = h32[mg * 64 + d];
                float rh = sg * hv;
                RHb[mg * 64 + d] = (__bf16)rh;
                RHbT[((size_t)(b * 64 + d)) * 1024 + j] = (__bf16)rh;
            } else {
                ubuf[mg * 64 + (d - 64)] = sg;
            }
        }
    }
}

// ---------------- FG2: fused agg2-GEMM + candidate gate + h-update (+proj) --
__global__ __launch_bounds__(512) void fg2(const __bf16* __restrict__ A,
        const __bf16* __restrict__ RHbT, const __bf16* __restrict__ RHb,
        float* __restrict__ h32,
        const __bf16* __restrict__ WcT0, const __bf16* __restrict__ WcT1,
        const float* __restrict__ Wc0, const float* __restrict__ Wc1,
        const float* __restrict__ bc,
        const float* __restrict__ xsrc, int xstride,
        const float* __restrict__ aggX, int axstride, int axoff,
        const float* __restrict__ ubuf, __bf16* __restrict__ HbT,
        const float* __restrict__ projw, const float* __restrict__ projb,
        float* __restrict__ outputs, float* __restrict__ yprevF,
        __bf16* __restrict__ yT, int mode, int hs) {
    __shared__ __align__(16) __bf16 As[2][2048];
    __shared__ __align__(16) __bf16 Bs[2][2048];
    __shared__ __align__(16) __bf16 Ag[64 * 64];
    __shared__ __align__(16) __bf16 Wt0[64 * 64];
    __shared__ __align__(16) __bf16 Wt1[64 * 64];
    __shared__ float Hn[64][65];
    __shared__ float xs[64], axs[64], w0x[64], w1x[64], bbs[64], pw[64];
    int t = threadIdx.x;
    int bm = blockIdx.x * 64;
    int b  = blockIdx.y;

    for (int i = t; i < 64 * 8; i += 512) {
        int n = i >> 3, seg = i & 7;
        int dst = n * 64 + (((seg + n) & 7) << 3);
        *(bf16x8*)&Wt0[dst] = *(const bf16x8*)&WcT0[n * 64 + seg * 8];
        *(bf16x8*)&Wt1[dst] = *(const bf16x8*)&WcT1[n * 64 + seg * 8];
    }
    if (t < 64) {
        int j = bm + t;
        xs[t] = (j < NN) ? xsrc[b * xstride + j] : 0.f;
        axs[t] = aggX[j * axstride + axoff + b];
    } else if (t < 128) {
        int d = t - 64;
        w0x[d] = Wc0[d]; w1x[d] = Wc1[d]; bbs[d] = bc[d];
    } else if (t < 192) {
        pw[t - 128] = projw[t - 128];
    }

    int half = t >> 8, tl = t & 255;
    int am = tl >> 2;
    int ag = ((tl & 3) - (am >> 1)) & 3;
    const __bf16* gp = half ? (RHbT + (size_t)(b * 64 + am) * 1024 + ag * 8)
                            : (A + (size_t)(bm + am) * 1024 + ag * 8);
    int ldso = tl * 8;
    int w = t >> 6, l = t & 63, lr = l & 15, lh = l >> 4;
    int wr = w & 3, wc = w >> 2;
    f32x4 acc[2];
    acc[0] = (f32x4){0.f, 0.f, 0.f, 0.f};
    acc[1] = (f32x4){0.f, 0.f, 0.f, 0.f};

    if (half) glds16(gp, &Bs[0][ldso]); else glds16(gp, &As[0][ldso]);
    __syncthreads();
    int cur = 0;
    for (int it = 0; it < 32; ++it) {
        if (it < 31) {
            if (half) glds16(gp + (it + 1) * 32, &Bs[cur ^ 1][ldso]);
            else      glds16(gp + (it + 1) * 32, &As[cur ^ 1][ldso]);
        }
        int arow = wr * 16 + lr;
        int asw = (lh + (arow >> 1)) & 3;
        bf16x8 af = *(const bf16x8*)&As[cur][arow * 32 + asw * 8];
#pragma unroll
        for (int ct = 0; ct < 2; ++ct) {
            int nrow = wc * 32 + ct * 16 + lr;
            int bsw = (lh + (nrow >> 1)) & 3;
            bf16x8 bv = *(const bf16x8*)&Bs[cur][nrow * 32 + bsw * 8];
            acc[ct] = __builtin_amdgcn_mfma_f32_16x16x32_bf16(af, bv, acc[ct], 0, 0, 0);
        }
        __syncthreads();
        cur ^= 1;
    }

#pragma unroll
    for (int ct = 0; ct < 2; ++ct)
#pragma unroll
        for (int r = 0; r < 4; ++r) {
            int m = wr * 16 + lh * 4 + r;
            int d = wc * 32 + ct * 16 + lr;
            Ag[m * 64 + ((((d >> 3) + m) & 7) << 3) + (d & 7)] = (__bf16)acc[ct][r];
        }
    __syncthreads();

    // gate GEMM: N=64, 2 col-tiles per wave
    f32x4 g[2];
    g[0] = (f32x4){0.f, 0.f, 0.f, 0.f};
    g[1] = (f32x4){0.f, 0.f, 0.f, 0.f};
    int arow2 = wr * 16 + lr;
    size_t mg2 = (size_t)((bm + arow2) * 16 + b);
#pragma unroll
    for (int h2 = 0; h2 < 2; ++h2) {
        bf16x8 ah = *(const bf16x8*)&RHb[mg2 * 64 + h2 * 32 + lh * 8];
        int sega = h2 * 4 + lh;
        bf16x8 agf = *(const bf16x8*)&Ag[arow2 * 64 + (((sega + arow2) & 7) << 3)];
#pragma unroll
        for (int ct = 0; ct < 2; ++ct) {
            int n = wc * 32 + ct * 16 + lr;
            int slot = n * 64 + (((sega + n) & 7) << 3);
            g[ct] = __builtin_amdgcn_mfma_f32_16x16x32_bf16(ah, *(const bf16x8*)&Wt0[slot], g[ct], 0, 0, 0);
            g[ct] = __builtin_amdgcn_mfma_f32_16x16x32_bf16(agf, *(const bf16x8*)&Wt1[slot], g[ct], 0, 0, 0);
        }
    }

#pragma unroll
    for (int ct = 0; ct < 2; ++ct) {
        int d = wc * 32 + ct * 16 + lr;
#pragma unroll
        for (int r = 0; r < 4; ++r) {
            int m = wr * 16 + lh * 4 + r;
            int j = bm + m;
            size_t mg = (size_t)(j * 16 + b);
            float pre = g[ct][r] + xs[m] * w0x[d] + axs[m] * w1x[d] + bbs[d];
            float cv = tanhf(pre);
            float u = ubuf[mg * 64 + d];
            float hold = h32[mg * 64 + d];
            float hn = u * hold + (1.f - u) * cv;
            h32[mg * 64 + d] = hn;
            HbT[((size_t)(b * 64 + d)) * 1024 + j] = (__bf16)hn;
            if (mode) Hn[m][d] = hn;
        }
    }
    if (mode) {
        __syncthreads();
        if (t < 64) {
            int m = t, j = bm + m;
            float acc2 = 0.f;
#pragma unroll
            for (int d = 0; d < 64; d++) acc2 += Hn[m][d] * pw[d];
            float y = acc2 + projb[0];
            yprevF[b * 1024 + j] = y;
            yT[b * 1024 + j] = (__bf16)y;
            if (j < NN) outputs[(b * HH + hs) * NN + j] = y;
        }
    }
}

// ---------------- loss ----------------
__global__ __launch_bounds__(256) void loss1(const float* __restrict__ outs,
        const float* __restrict__ tgt, float* __restrict__ part) {
    __shared__ float red[256];
    int t = blockIdx.x * 256 + threadIdx.x;
    float s = 0.f;
    for (int i = t; i < BB * HH * NN; i += 256 * 256) {
        float dd = outs[i] - tgt[i];
        s += dd * dd;
    }
    red[threadIdx.x] = s;
    __syncthreads();
    for (int w = 128; w > 0; w >>= 1) {
        if (threadIdx.x < w) red[threadIdx.x] += red[threadIdx.x + w];
        __syncthreads();
    }
    if (threadIdx.x == 0) part[blockIdx.x] = red[0];
}

__global__ __launch_bounds__(256) void loss2(const float* __restrict__ part,
        float* __restrict__ loss) {
    __shared__ double red[256];
    int t = threadIdx.x;
    red[t] = (double)part[t];
    __syncthreads();
    for (int w = 128; w > 0; w >>= 1) {
        if (t < w) red[t] += red[t + w];
        __syncthreads();
    }
    if (t == 0) loss[0] = (float)(red[0] / (double)(BB * HH * NN));
}

// ---------------- host ----------------
extern "C" void kernel_launch(void* const* d_in, const int* in_sizes, int n_in,
                              void* d_out, int out_size, void* d_ws, size_t ws_size,
                              hipStream_t stream) {
    const float* inputs  = (const float*)d_in[0];
    const float* ein     = (const float*)d_in[1];
    const float* targets = (const float*)d_in[2];
    const float* u_noise = (const float*)d_in[3];
    const float* c1w = (const float*)d_in[4];
    const float* c1b = (const float*)d_in[5];
    const float* c2w = (const float*)d_in[6];
    const float* c2b = (const float*)d_in[7];
    const float* fcw = (const float*)d_in[8];
    const float* fcb = (const float*)d_in[9];
    const float* Wa  = (const float*)d_in[10];
    const float* Wb  = (const float*)d_in[11];
    const float* b1  = (const float*)d_in[12];
    const float* W2  = (const float*)d_in[13];
    const float* b2  = (const float*)d_in[14];
    const float* eWru0 = (const float*)d_in[15];
    const float* eWru1 = (const float*)d_in[16];
    const float* ebru  = (const float*)d_in[17];
    const float* eWc0  = (const float*)d_in[18];
    const float* eWc1  = (const float*)d_in[19];
    const float* ebc   = (const float*)d_in[20];
    const float* dWru0 = (const float*)d_in[21];
    const float* dWru1 = (const float*)d_in[22];
    const float* dbru  = (const float*)d_in[23];
    const float* dWc0  = (const float*)d_in[24];
    const float* dWc1  = (const float*)d_in[25];
    const float* dbc   = (const float*)d_in[26];
    const float* projw = (const float*)d_in[27];
    const float* projb = (const float*)d_in[28];

    float* out = (float*)d_out;
    float* mask    = out;
    float* outputs = out + NN * NN;
    float* loss    = out + NN * NN + BB * HH * NN;

    float* ws = (float*)d_ws;
    float* f_raw = ws;                        // 16,000
    float* fbuf  = ws + 16000;                // 128,000
    float* fa    = ws + 144000;               // 128,000
    float* fb    = ws + 272000;               // 128,000
    float* deg   = ws + 400000;               // 1,024
    float* lossp = ws + 401024;               // 256
    __bf16* wp   = (__bf16*)(ws + 401280);    // 49,152 bf16
    __bf16* A_bf = (__bf16*)(ws + 425856);    // 1,048,576 bf16
    __bf16* XeT  = (__bf16*)(ws + 950144);    // 196,608 bf16
    float* aggXe = ws + 1048448;              // 196,608 f32
    __bf16* RHb  = (__bf16*)(ws + 1245056);   // 1,048,576 bf16
    __bf16* RHbT = (__bf16*)(ws + 1769344);   // 1,048,576 bf16
    float* ubuf  = ws + 2293632;              // 1,048,576 f32
    float* h32   = ws + 3342208;              // 1,048,576 f32   <- zero region
    float* yprevF= ws + 4390784;              // 16,384 f32
    float* aggXd = ws + 4407168;              // 65,536 f32
    __bf16* HbT  = (__bf16*)(ws + 4472704);   // 1,048,576 bf16
    __bf16* yT   = (__bf16*)(ws + 4996992);   // 65,536 bf16
    const int ZLEN = 5029760 - 3342208;       // zero words

    __bf16 *eW0T = wp, *eW1T = wp + 8192, *eWc0T = wp + 16384, *eWc1T = wp + 20480;
    __bf16 *dW0T = wp + 24576, *dW1T = wp + 32768, *dWc0T = wp + 40960, *dWc1T = wp + 45056;

    init_zero<<<2048, 256, 0, stream>>>(h32, ZLEN);
    prep_w<<<192, 256, 0, stream>>>(eWru0, eWru1, eWc0, eWc1, dWru0, dWru1, dWc0, dWc1, wp);
    prep_xe<<<768, 256, 0, stream>>>(inputs, XeT);

    // graph head
    s1_conv<<<NN, 256, 0, stream>>>(ein, c1w, c1b, c2w, c2b, f_raw);
    fc_relu<<<NN, 128, 0, stream>>>(f_raw, fcw, fcb, fbuf);
    fafb_k<<<NN, 128, 0, stream>>>(fbuf, Wa, Wb, fa, fb);
    edge_mask<<<dim3(63, 63), 256, 0, stream>>>(fa, fb, b1, W2, b2, u_noise, mask);
    row_deg<<<NN, 256, 0, stream>>>(mask, deg);
    make_A<<<4096, 256, 0, stream>>>(mask, deg, A_bf);

    // x-aggregation for all encoder steps: aggXe[j][s*16+b] = (A @ x_s)[j,b]
    gemm_bf<<<dim3(16, 3), 256, 0, stream>>>(A_bf, XeT, aggXe, 192);

    // encoder
    for (int s = 0; s < SS; s++) {
        fg1<<<dim3(16, 16), 512, 0, stream>>>(A_bf, HbT, h32, eW0T, eW1T,
                eWru0, eWru1, ebru, inputs + s * NN, SS * NN, aggXe, 192, s * 16,
                RHb, RHbT, ubuf);
        fg2<<<dim3(16, 16), 512, 0, stream>>>(A_bf, RHbT, RHb, h32, eWc0T, eWc1T,
                eWc0, eWc1, ebc, inputs + s * NN, SS * NN, aggXe, 192, s * 16,
                ubuf, HbT, projw, projb, outputs, yprevF, yT, 0, 0);
    }
    // decoder
    for (int k = 0; k < HH; k++) {
        fg1<<<dim3(16, 16), 512, 0, stream>>>(A_bf, HbT, h32, dW0T, dW1T,
                dWru0, dWru1, dbru, yprevF, 1024, aggXd, 64, 0,
                RHb, RHbT, ubuf);
        fg2<<<dim3(16, 16), 512, 0, stream>>>(A_bf, RHbT, RHb, h32, dWc0T, dWc1T,
                dWc0, dWc1, dbc, yprevF, 1024, aggXd, 64, 0,
                ubuf, HbT, projw, projb, outputs, yprevF, yT, 1, k);
        if (k < HH - 1)
            gemm_bf<<<dim3(16, 1), 256, 0, stream>>>(A_bf, yT, aggXd, 64);
    }

    loss1<<<256, 256, 0, stream>>>(outputs, targets, lossp);
    loss2<<<1, 256, 0, stream>>>(lossp, loss);
}